// Round 1
// 434.568 us; speedup vs baseline: 1.0610x; 1.0610x over previous
//
#include <hip/hip_runtime.h>
#include <cstddef>

constexpr int NN     = 8192;
constexpr int DIN    = 1024;
constexpr int DMID   = 256;
constexpr int DEMB   = 64;
constexpr int NEDGE  = 65536;
constexpr int MAXDEG = 64;   // max in-degree; Poisson(8) tail P(>64) ~ 1e-27

typedef __attribute__((ext_vector_type(8))) short bf16x8;
typedef __attribute__((ext_vector_type(4))) float f32x4;
#define MFMA16(a, b, c) __builtin_amdgcn_mfma_f32_16x16x32_bf16((a), (b), (c), 0, 0, 0)

__device__ __forceinline__ unsigned short bf16_rne(float x) {
  unsigned u = __float_as_uint(x);
  return (unsigned short)((u + 0x7FFFu + ((u >> 16) & 1u)) >> 16);
}
__device__ __forceinline__ float bf16_tof(unsigned short h) {
  return __uint_as_float((unsigned)h << 16);
}

// ---------------- prep: W1T/W2T transpose+round, X->bf16, zero cursor/rowsum ---------
constexpr int WCONV_BLOCKS = (DMID * DIN + DEMB * DMID) / 256;   // 1088
constexpr int XCONV_BLOCKS = NN * DIN / (256 * 8);               // 4096
constexpr int ZERO_BLOCKS  = 16;                                 // 64 KiB of int4
__global__ __launch_bounds__(256) void prep_kernel(const float* __restrict__ W1,
                                                   const float* __restrict__ W2,
                                                   const float* __restrict__ X,
                                                   unsigned short* __restrict__ W1b,
                                                   unsigned short* __restrict__ W2b,
                                                   unsigned short* __restrict__ Xb,
                                                   int* __restrict__ zero_base)
{
  int b = blockIdx.x;
  if (b < WCONV_BLOCKS) {
    int idx = b * 256 + threadIdx.x;
    if (idx < DMID * DIN) {                  // W1T [256][1024]
      int n = idx >> 10, k = idx & 1023;
      W1b[idx] = bf16_rne(W1[k * DMID + n]);
    } else {                                 // W2T [64][256]
      int t = idx - DMID * DIN;
      int n = t >> 8, k = t & 255;
      W2b[t] = bf16_rne(W2[k * DEMB + n]);
    }
  } else if (b < WCONV_BLOCKS + XCONV_BLOCKS) {
    int idx = (b - WCONV_BLOCKS) * 2048 + threadIdx.x * 8;
    float4 x0 = *(const float4*)(X + idx);
    float4 x1 = *(const float4*)(X + idx + 4);
    bf16x8 h;
    h[0] = (short)bf16_rne(x0.x); h[1] = (short)bf16_rne(x0.y);
    h[2] = (short)bf16_rne(x0.z); h[3] = (short)bf16_rne(x0.w);
    h[4] = (short)bf16_rne(x1.x); h[5] = (short)bf16_rne(x1.y);
    h[6] = (short)bf16_rne(x1.z); h[7] = (short)bf16_rne(x1.w);
    *(bf16x8*)(Xb + idx) = h;
  } else {                                   // zero cursor||rowsum (adjacent, 64 KiB)
    int idx = (b - WCONV_BLOCKS - XCONV_BLOCKS) * 1024 + threadIdx.x * 4;
    *(int4*)(zero_base + idx) = make_int4(0, 0, 0, 0);
  }
}

// ---------------- ELL build: no scan, no CSR. cursor ends up holding degree --------
__global__ __launch_bounds__(256) void build_ell_kernel(
    const int* __restrict__ esrc, const float* __restrict__ ev,
    const int* __restrict__ edst, int* __restrict__ cursor,
    int* __restrict__ ell_src, float* __restrict__ ell_val)
{
  int e = blockIdx.x * 256 + threadIdx.x;
  int d = edst[e];
  int pos = atomicAdd(&cursor[d], 1);
  if (pos < MAXDEG) {
    ell_src[d * MAXDEG + pos] = esrc[e];
    ell_val[d * MAXDEG + pos] = ev[e];
  }
}

// ---------------- GEMM1: G1 = bf16(Xb @ W1); grid (m=128, n=4) for XCD sharing -----
__global__ __launch_bounds__(256) void gemm1_kernel(
    const unsigned short* __restrict__ Xb, const unsigned short* __restrict__ W1b,
    unsigned short* __restrict__ G1)
{
  const int lane = threadIdx.x & 63;
  const int wave = threadIdx.x >> 6;
  const int m0 = blockIdx.x * 64 + wave * 16;
  const int n0 = blockIdx.y * 64;
  const int rl = lane & 15;
  const int kq = (lane >> 4) * 8;
  f32x4 zero = {0.f, 0.f, 0.f, 0.f};
  f32x4 acc[4] = {zero, zero, zero, zero};
  for (int s = 0; s < DIN / 32; ++s) {
    const int kb = s * 32 + kq;
    bf16x8 ah = *(const bf16x8*)(Xb + (size_t)(m0 + rl) * DIN + kb);
#pragma unroll
    for (int ns = 0; ns < 4; ++ns) {
      bf16x8 bh = *(const bf16x8*)(W1b + (size_t)(n0 + ns * 16 + rl) * DIN + kb);
      acc[ns] = MFMA16(ah, bh, acc[ns]);
    }
  }
  const int rq = (lane >> 4) * 4;
#pragma unroll
  for (int ns = 0; ns < 4; ++ns)
#pragma unroll
    for (int r = 0; r < 4; ++r)
      G1[(size_t)(m0 + rq + r) * DMID + n0 + ns * 16 + rl] = bf16_rne(acc[ns][r]);
}

// ---------------- fused spmm1 + gemm2: H rows in LDS, then MFMA vs W2T -> E1 -------
__global__ __launch_bounds__(256) void spmm1_gemm2_kernel(
    const unsigned short* __restrict__ G1, const int* __restrict__ deg,
    const int* __restrict__ ell_src, const float* __restrict__ ell_val,
    const unsigned short* __restrict__ W2b, float* __restrict__ E1)
{
  __shared__ unsigned short Hs[16][DMID + 8];   // +8 shorts: 528B stride, 2-way banks
  const int lane = threadIdx.x & 63;
  const int wave = threadIdx.x >> 6;
  const int r0 = blockIdx.x * 16;
  const int c = lane * 4;
#pragma unroll
  for (int rr = 0; rr < 4; ++rr) {
    const int row = wave * 4 + rr;
    const int r = r0 + row;
    const int dg = min(deg[r], MAXDEG);
    const int* sp = ell_src + (size_t)r * MAXDEG;
    const float* vp = ell_val + (size_t)r * MAXDEG;
    float4 acc = make_float4(0.f, 0.f, 0.f, 0.f);
    for (int e = 0; e < dg; ++e) {
      const int s = sp[e];
      const float v = vp[e];
      ushort4 h = *(const ushort4*)(G1 + (size_t)s * DMID + c);
      acc.x = fmaf(v, bf16_tof(h.x), acc.x);
      acc.y = fmaf(v, bf16_tof(h.y), acc.y);
      acc.z = fmaf(v, bf16_tof(h.z), acc.z);
      acc.w = fmaf(v, bf16_tof(h.w), acc.w);
    }
    ushort4 hq;
    hq.x = bf16_rne(fmaxf(acc.x, 0.f));
    hq.y = bf16_rne(fmaxf(acc.y, 0.f));
    hq.z = bf16_rne(fmaxf(acc.z, 0.f));
    hq.w = bf16_rne(fmaxf(acc.w, 0.f));
    *(ushort4*)(&Hs[row][c]) = hq;
  }
  __syncthreads();
  const int rl = lane & 15;
  const int kq = (lane >> 4) * 8;
  f32x4 acc4 = {0.f, 0.f, 0.f, 0.f};
#pragma unroll
  for (int s = 0; s < DMID / 32; ++s) {
    const int kb = s * 32 + kq;
    bf16x8 a = *(const bf16x8*)(&Hs[rl][kb]);
    bf16x8 b = *(const bf16x8*)(W2b + (size_t)(wave * 16 + rl) * DMID + kb);
    acc4 = MFMA16(a, b, acc4);
  }
  const int rq = (lane >> 4) * 4;
#pragma unroll
  for (int r = 0; r < 4; ++r)
    E1[(size_t)(r0 + rq + r) * DEMB + wave * 16 + rl] = acc4[r];
}

// ---------------- spmm2: EmbH = bf16(spmm(E1)); sq from ROUNDED value --------------
__global__ __launch_bounds__(256) void spmm2_kernel(
    const float* __restrict__ H, const int* __restrict__ deg,
    const int* __restrict__ ell_src, const float* __restrict__ ell_val,
    unsigned short* __restrict__ EmbH, float* __restrict__ sqv)
{
  const int lane = threadIdx.x & 63;
  const int wave = threadIdx.x >> 6;
  const int r = blockIdx.x * 4 + wave;
  const int dg = min(deg[r], MAXDEG);
  const int* sp = ell_src + (size_t)r * MAXDEG;
  const float* vp = ell_val + (size_t)r * MAXDEG;
  float acc = 0.f;
  for (int e = 0; e < dg; ++e)
    acc = fmaf(vp[e], H[(size_t)sp[e] * DEMB + lane], acc);
  unsigned short h = bf16_rne(acc);
  EmbH[(size_t)r * DEMB + lane] = h;
  float hf = bf16_tof(h);
  float sq = hf * hf;
#pragma unroll
  for (int off = 32; off; off >>= 1) sq += __shfl_xor(sq, off, 64);
  if (lane == 0) sqv[r] = sq;
}

// ---------------- pass1: strip rowsum. Block owns 128 rows x 1024 cols, register acc
__global__ __launch_bounds__(256) void rowsum_kernel(
    const unsigned short* __restrict__ EH, const float* __restrict__ sq,
    float* __restrict__ rowsum)
{
  const int lane = threadIdx.x & 63;
  const int wave = threadIdx.x >> 6;
  const int wr = wave >> 1, wc = wave & 1;
  const int ibase = blockIdx.y * 128 + wr * 64;
  const int rl = lane & 15;
  const int kq = (lane >> 4) * 8;
  const int rq = (lane >> 4) * 4;

  bf16x8 a[2][4];                          // A-fragments loaded once per block
#pragma unroll
  for (int s = 0; s < 2; ++s)
#pragma unroll
    for (int t = 0; t < 4; ++t)
      a[s][t] = *(const bf16x8*)(EH + (size_t)(ibase + t * 16 + rl) * DEMB + s * 32 + kq);

  float si[4][4];
#pragma unroll
  for (int ms = 0; ms < 4; ++ms)
#pragma unroll
    for (int r = 0; r < 4; ++r) si[ms][r] = sq[ibase + ms * 16 + rq + r];

  float rs[4][4] = {};
  for (int jt = 0; jt < 8; ++jt) {
    const int jbase = blockIdx.x * 1024 + jt * 128 + wc * 64;
    float sj[4];
#pragma unroll
    for (int ns = 0; ns < 4; ++ns) sj[ns] = sq[jbase + ns * 16 + rl];
    f32x4 zero = {0.f, 0.f, 0.f, 0.f};
    f32x4 acc[4][4];
#pragma unroll
    for (int ms = 0; ms < 4; ++ms)
#pragma unroll
      for (int ns = 0; ns < 4; ++ns) acc[ms][ns] = zero;
#pragma unroll
    for (int s = 0; s < 2; ++s) {
      bf16x8 b[4];
#pragma unroll
      for (int t = 0; t < 4; ++t)
        b[t] = *(const bf16x8*)(EH + (size_t)(jbase + t * 16 + rl) * DEMB + s * 32 + kq);
#pragma unroll
      for (int ms = 0; ms < 4; ++ms)
#pragma unroll
        for (int ns = 0; ns < 4; ++ns)
          acc[ms][ns] = MFMA16(a[s][ms], b[ns], acc[ms][ns]);
    }
#pragma unroll
    for (int ms = 0; ms < 4; ++ms)
#pragma unroll
      for (int ns = 0; ns < 4; ++ns)
#pragma unroll
        for (int r = 0; r < 4; ++r)
          rs[ms][r] += __expf(fmaf(2.f, acc[ms][ns][r], -si[ms][r] - sj[ns]));
  }
  // reduce across rl within quad, one lightly-contended atomic per row (16/addr total)
#pragma unroll
  for (int ms = 0; ms < 4; ++ms)
#pragma unroll
    for (int r = 0; r < 4; ++r) {
      float v = rs[ms][r];
      v += __shfl_xor(v, 1, 64);
      v += __shfl_xor(v, 2, 64);
      v += __shfl_xor(v, 4, 64);
      v += __shfl_xor(v, 8, 64);
      if (rl == 0) atomicAdd(&rowsum[ibase + ms * 16 + rq + r], v);
    }
}

// ---------------- shared 64x64 tile: acc[ms][ns] = Emb_i . Emb_j (K=64) ------------
__device__ __forceinline__ void dist_tile_hh(
    const unsigned short* __restrict__ EH, int ibase, int jbase, int lane,
    f32x4 (&acc)[4][4])
{
  const int rl = lane & 15;
  const int kq = (lane >> 4) * 8;
#pragma unroll
  for (int s = 0; s < 2; ++s) {
    const int kb = s * 32 + kq;
    bf16x8 a[4], b[4];
#pragma unroll
    for (int t = 0; t < 4; ++t) {
      a[t] = *(const bf16x8*)(EH + (size_t)(ibase + t * 16 + rl) * DEMB + kb);
      b[t] = *(const bf16x8*)(EH + (size_t)(jbase + t * 16 + rl) * DEMB + kb);
    }
#pragma unroll
    for (int ms = 0; ms < 4; ++ms)
#pragma unroll
      for (int ns = 0; ns < 4; ++ns)
        acc[ms][ns] = MFMA16(a[ms], b[ns], acc[ms][ns]);
  }
}

// ---------------- pass2: full grid, recompute e, nontemporal streaming stores ------
__global__ __launch_bounds__(256) void dist_write_kernel(
    const unsigned short* __restrict__ EH, const float* __restrict__ sq,
    const float* __restrict__ rowsum, float* __restrict__ out)
{
  const int lane = threadIdx.x & 63;
  const int wave = threadIdx.x >> 6;
  const int wr = wave >> 1, wc = wave & 1;
  const int ibase = blockIdx.y * 128 + wr * 64;
  const int jbase = blockIdx.x * 128 + wc * 64;
  const int rl = lane & 15;
  const int rq = (lane >> 4) * 4;

  f32x4 zero = {0.f, 0.f, 0.f, 0.f};
  f32x4 acc[4][4];
#pragma unroll
  for (int ms = 0; ms < 4; ++ms)
#pragma unroll
    for (int ns = 0; ns < 4; ++ns) acc[ms][ns] = zero;
  dist_tile_hh(EH, ibase, jbase, lane, acc);

  float si[4][4], ri[4][4], sj[4];
#pragma unroll
  for (int ms = 0; ms < 4; ++ms)
#pragma unroll
    for (int r = 0; r < 4; ++r) {
      const int i = ibase + ms * 16 + rq + r;
      si[ms][r] = sq[i];
      ri[ms][r] = 1.f / rowsum[i];
    }
#pragma unroll
  for (int ns = 0; ns < 4; ++ns) sj[ns] = sq[jbase + ns * 16 + rl];

#pragma unroll
  for (int ms = 0; ms < 4; ++ms)
#pragma unroll
    for (int r = 0; r < 4; ++r) {
      const size_t row = (size_t)(ibase + ms * 16 + rq + r) * NN;
#pragma unroll
      for (int ns = 0; ns < 4; ++ns) {
        float e = __expf(fmaf(2.f, acc[ms][ns][r], -si[ms][r] - sj[ns]));
        __builtin_nontemporal_store(fmaf(e, ri[ms][r], 1e-10f),
                                    &out[row + jbase + ns * 16 + rl]);
      }
    }
}

// ---------------- launch ----------------
extern "C" void kernel_launch(void* const* d_in, const int* in_sizes, int n_in,
                              void* d_out, int out_size, void* d_ws, size_t ws_size,
                              hipStream_t stream)
{
  const float* X  = (const float*)d_in[0];
  const float* W1 = (const float*)d_in[1];
  const float* W2 = (const float*)d_in[2];
  const float* ev = (const float*)d_in[3];
  const int* esrc = (const int*)d_in[4];
  const int* edst = (const int*)d_in[5];
  float* out = (float*)d_out;

  char* p = (char*)d_ws;
  auto alloc = [&](size_t bytes) { char* q = p; p += (bytes + 255) & ~(size_t)255; return q; };

  // cursor and rowsum adjacent: zeroed as one 64 KiB region inside prep
  int*   cursor  = (int*)alloc(NN * 4);
  float* rowsum  = (float*)alloc(NN * 4);
  float* sqv     = (float*)alloc(NN * 4);
  float* E1      = (float*)alloc((size_t)NN * DEMB * 4);
  unsigned short* W1b  = (unsigned short*)alloc((size_t)DMID * DIN * 2);
  unsigned short* W2b  = (unsigned short*)alloc((size_t)DEMB * DMID * 2);
  unsigned short* Xb   = (unsigned short*)alloc((size_t)NN * DIN * 2);
  unsigned short* G1   = (unsigned short*)alloc((size_t)NN * DMID * 2);
  unsigned short* EmbH = (unsigned short*)alloc((size_t)NN * DEMB * 2);
  int*   ell_src = (int*)alloc((size_t)NN * MAXDEG * 4);
  float* ell_val = (float*)alloc((size_t)NN * MAXDEG * 4);

  prep_kernel<<<WCONV_BLOCKS + XCONV_BLOCKS + ZERO_BLOCKS, 256, 0, stream>>>(
      W1, W2, X, W1b, W2b, Xb, cursor);
  build_ell_kernel<<<NEDGE / 256, 256, 0, stream>>>(esrc, ev, edst, cursor,
                                                    ell_src, ell_val);

  gemm1_kernel<<<dim3(NN / 64, DMID / 64), 256, 0, stream>>>(Xb, W1b, G1);
  spmm1_gemm2_kernel<<<NN / 16, 256, 0, stream>>>(G1, cursor, ell_src, ell_val,
                                                  W2b, E1);
  spmm2_kernel<<<NN / 4, 256, 0, stream>>>(E1, cursor, ell_src, ell_val, EmbH, sqv);

  rowsum_kernel<<<dim3(8, NN / 128), 256, 0, stream>>>(EmbH, sqv, rowsum);
  dist_write_kernel<<<dim3(NN / 128, NN / 128), 256, 0, stream>>>(EmbH, sqv, rowsum, out);
}